// Round 11
// baseline (342.439 us; speedup 1.0000x reference)
//
#include <hip/hip_runtime.h>

// Problem constants (from reference): B=32, A=262144, K=131072.
#define A_ELEMS   262144
#define A_SHIFT   18        // log2(A_ELEMS)
#define K_ELEMS   131072
#define UNROLL    4

typedef float v4f __attribute__((ext_vector_type(4)));  // native vector: ok for nontemporal builtin

__global__ void zero_ws_kernel(float* ws) {
    ws[0] = 0.0f;   // loss sum
    ws[1] = 0.0f;   // mask count
}

__global__ __launch_bounds__(256) void regloss_main_kernel(
    const float* __restrict__ input,    // (B, 2*K) f32
    const v4f* __restrict__ target,     // (B*A) x (x, y, idx, state)
    float* __restrict__ ws,
    long long N)                        // B*A
{
    long long tid    = (long long)blockIdx.x * blockDim.x + threadIdx.x;
    long long stride = (long long)gridDim.x * blockDim.x;

    float loss = 0.0f;
    float cnt  = 0.0f;

    for (long long base = tid; base < N; base += stride * UNROLL) {
        // Stage 1: issue UNROLL independent target loads (non-temporal:
        // stream-once data, keep L2 for the gather window).
        v4f t[UNROLL];
        #pragma unroll
        for (int u = 0; u < UNROLL; ++u) {
            long long i  = base + (long long)u * stride;
            long long is = (i < N) ? i : (N - 1);
            t[u] = __builtin_nontemporal_load(&target[is]);
        }

        // Stage 2: issue all gathers unconditionally (clamped addresses),
        // no divergent branch between them -> up to 2*UNROLL loads in flight.
        float g0[UNROLL], g1[UNROLL], m[UNROLL];
        #pragma unroll
        for (int u = 0; u < UNROLL; ++u) {
            long long i  = base + (long long)u * stride;
            long long is = (i < N) ? i : (N - 1);
            int b   = (int)(is >> A_SHIFT);
            int idx = (int)t[u].z;
            idx = min(max(idx, 0), K_ELEMS - 1);
            const float* inb = input + (long long)b * (2 * K_ELEMS);
            g0[u] = inb[idx];                // regression[b,0,idx]
            g1[u] = inb[K_ELEMS + idx];      // regression[b,1,idx]
            m[u]  = ((i < N) && (t[u].w == 1.0f)) ? 1.0f : 0.0f;
        }

        // Stage 3: compute (waits resolve here, overlapped across 8 loads).
        #pragma unroll
        for (int u = 0; u < UNROLL; ++u) {
            float dx = g0[u] - t[u].x;
            float dy = g1[u] - t[u].y;
            float adx = fabsf(dx);
            float ady = fabsf(dy);
            float lx = (adx < 1.0f) ? 0.5f * dx * dx : adx - 0.5f;
            float ly = (ady < 1.0f) ? 0.5f * dy * dy : ady - 0.5f;
            loss += m[u] * (lx + ly);
            cnt  += m[u];
        }
    }

    // Wave-64 butterfly reduce
    #pragma unroll
    for (int off = 32; off > 0; off >>= 1) {
        loss += __shfl_down(loss, off, 64);
        cnt  += __shfl_down(cnt,  off, 64);
    }

    __shared__ float sl[4];
    __shared__ float sc[4];
    int wave = threadIdx.x >> 6;
    int lane = threadIdx.x & 63;
    if (lane == 0) { sl[wave] = loss; sc[wave] = cnt; }
    __syncthreads();
    if (threadIdx.x == 0) {
        float L = sl[0] + sl[1] + sl[2] + sl[3];
        float C = sc[0] + sc[1] + sc[2] + sc[3];
        atomicAdd(&ws[0], L);
        atomicAdd(&ws[1], C);
    }
}

__global__ void finalize_kernel(const float* __restrict__ ws,
                                float* __restrict__ out) {
    const float POLY_WEIGHT = 1.0f;
    out[0] = ws[0] / fmaxf(1.0f, ws[1]) * POLY_WEIGHT;
}

extern "C" void kernel_launch(void* const* d_in, const int* in_sizes, int n_in,
                              void* d_out, int out_size, void* d_ws, size_t ws_size,
                              hipStream_t stream) {
    const float* input  = (const float*)d_in[0];         // (B, 2K) f32
    const v4f*   target = (const v4f*)d_in[1];           // (B, A, 4) f32
    float* out = (float*)d_out;
    float* ws  = (float*)d_ws;

    long long N = (long long)in_sizes[1] / 4;            // B*A elements

    zero_ws_kernel<<<1, 1, 0, stream>>>(ws);

    // 2048 blocks: 8 blocks/CU; grid-stride keeps the concurrent gather
    // window at ~2 batches (2 MB) -> L2-resident.
    regloss_main_kernel<<<2048, 256, 0, stream>>>(input, target, ws, N);

    finalize_kernel<<<1, 1, 0, stream>>>(ws, out);
}

// Round 12
// 295.386 us; speedup vs baseline: 1.1593x; 1.1593x over previous
//
#include <hip/hip_runtime.h>

// Problem constants (from reference): B=32, A=262144, K=131072.
#define B_BATCH   32
#define A_ELEMS   262144
#define A_SHIFT   18
#define K_ELEMS   131072
#define NPOS      ((long long)B_BATCH * A_ELEMS)   // 8388608

typedef float v4f __attribute__((ext_vector_type(4)));

__global__ void zero_ws_kernel(float* ws) {
    ws[0] = 0.0f;   // loss sum
    ws[1] = 0.0f;   // mask count
}

// Batch-partitioned kernel. blockIdx -> XCD is round-robin (bid & 7, m09);
// XCD x owns batches b == x (mod 8), processed sequentially (g = 0..3), so
// the per-XCD instantaneous gather window is ONE batch's input region
// (1 MB) -> resident in the 4 MB per-XCD L2. Round-11 lesson: stride-spread
// unrolling made the window 8 MB and tripled FETCH_SIZE.
__global__ __launch_bounds__(256) void regloss_batched_kernel(
    const float* __restrict__ input,    // (B, 2*K) f32
    const v4f*  __restrict__ target,    // (B*A) x (x, y, idx, state)
    float* __restrict__ ws)
{
    const int tid = threadIdx.x;
    const int xcd = blockIdx.x & 7;
    const int j   = blockIdx.x >> 3;    // 0..255

    float loss = 0.0f;
    float cnt  = 0.0f;

    #pragma unroll
    for (int g = 0; g < 4; ++g) {
        const int batch = xcd + 8 * g;
        const float* __restrict__ inb = input + (size_t)batch * (2 * K_ELEMS);
        const size_t pos = (size_t)batch * A_ELEMS + (size_t)j * 1024
                         + (size_t)tid * 4;

        // 64 B of contiguous targets per thread (4 independent dwordx4),
        // non-temporal: stream-once, don't evict the gather window from L2.
        v4f t[4];
        #pragma unroll
        for (int u = 0; u < 4; ++u)
            t[u] = __builtin_nontemporal_load(&target[pos + u]);

        // Unconditional clamped gathers, batch-local (L2-resident window).
        float g0[4], g1[4], m[4];
        #pragma unroll
        for (int u = 0; u < 4; ++u) {
            int idx = (int)t[u].z;
            idx = min(max(idx, 0), K_ELEMS - 1);
            g0[u] = inb[idx];               // regression[b,0,idx]
            g1[u] = inb[K_ELEMS + idx];     // regression[b,1,idx]
            m[u]  = (t[u].w == 1.0f) ? 1.0f : 0.0f;
        }

        #pragma unroll
        for (int u = 0; u < 4; ++u) {
            float dx = g0[u] - t[u].x;
            float dy = g1[u] - t[u].y;
            float adx = fabsf(dx), ady = fabsf(dy);
            float lx = (adx < 1.0f) ? 0.5f * dx * dx : adx - 0.5f;
            float ly = (ady < 1.0f) ? 0.5f * dy * dy : ady - 0.5f;
            loss += m[u] * (lx + ly);
            cnt  += m[u];
        }
    }

    // Wave-64 butterfly reduce
    #pragma unroll
    for (int off = 32; off > 0; off >>= 1) {
        loss += __shfl_down(loss, off, 64);
        cnt  += __shfl_down(cnt,  off, 64);
    }
    __shared__ float sl[4], sc[4];
    const int wave = tid >> 6, lane = tid & 63;
    if (lane == 0) { sl[wave] = loss; sc[wave] = cnt; }
    __syncthreads();
    if (tid == 0) {
        atomicAdd(&ws[0], sl[0] + sl[1] + sl[2] + sl[3]);
        atomicAdd(&ws[1], sc[0] + sc[1] + sc[2] + sc[3]);
    }
}

// Generic fallback (Round-7 proven-correct structure) if sizes differ.
__global__ __launch_bounds__(256) void regloss_generic_kernel(
    const float* __restrict__ input,
    const v4f* __restrict__ target,
    float* __restrict__ ws,
    long long N, int K, int ashift)
{
    long long tid    = (long long)blockIdx.x * blockDim.x + threadIdx.x;
    long long stride = (long long)gridDim.x * blockDim.x;
    float loss = 0.0f, cnt = 0.0f;
    for (long long i = tid; i < N; i += stride) {
        v4f t = target[i];
        if (t.w == 1.0f) {
            int b   = (int)(i >> ashift);
            int idx = min(max((int)t.z, 0), K - 1);
            const float* inb = input + (long long)b * (2LL * K);
            float dx = inb[idx] - t.x;
            float dy = inb[K + idx] - t.y;
            float adx = fabsf(dx), ady = fabsf(dy);
            loss += (adx < 1.0f) ? 0.5f * dx * dx : adx - 0.5f;
            loss += (ady < 1.0f) ? 0.5f * dy * dy : ady - 0.5f;
            cnt  += 1.0f;
        }
    }
    #pragma unroll
    for (int off = 32; off > 0; off >>= 1) {
        loss += __shfl_down(loss, off, 64);
        cnt  += __shfl_down(cnt,  off, 64);
    }
    __shared__ float sl[4], sc[4];
    int wave = threadIdx.x >> 6, lane = threadIdx.x & 63;
    if (lane == 0) { sl[wave] = loss; sc[wave] = cnt; }
    __syncthreads();
    if (threadIdx.x == 0) {
        atomicAdd(&ws[0], sl[0] + sl[1] + sl[2] + sl[3]);
        atomicAdd(&ws[1], sc[0] + sc[1] + sc[2] + sc[3]);
    }
}

__global__ void finalize_kernel(const float* __restrict__ ws,
                                float* __restrict__ out) {
    const float POLY_WEIGHT = 1.0f;
    out[0] = ws[0] / fmaxf(1.0f, ws[1]) * POLY_WEIGHT;
}

extern "C" void kernel_launch(void* const* d_in, const int* in_sizes, int n_in,
                              void* d_out, int out_size, void* d_ws, size_t ws_size,
                              hipStream_t stream) {
    const float* input  = (const float*)d_in[0];   // (B, 2K) f32
    const v4f*   target = (const v4f*)d_in[1];     // (B, A, 4) f32
    float* out = (float*)d_out;
    float* ws  = (float*)d_ws;

    long long N = (long long)in_sizes[1] / 4;      // B*A

    zero_ws_kernel<<<1, 1, 0, stream>>>(ws);

    if (N == NPOS && in_sizes[0] == 2 * K_ELEMS * B_BATCH) {
        regloss_batched_kernel<<<2048, 256, 0, stream>>>(input, target, ws);
    } else {
        regloss_generic_kernel<<<2048, 256, 0, stream>>>(input, target, ws,
                                                         N, K_ELEMS, A_SHIFT);
    }

    finalize_kernel<<<1, 1, 0, stream>>>(ws, out);
}

// Round 13
// 260.145 us; speedup vs baseline: 1.3163x; 1.1355x over previous
//
#include <hip/hip_runtime.h>

// Problem constants (from reference): B=32, A=262144, K=131072.
#define B_BATCH   32
#define A_ELEMS   262144
#define A_SHIFT   18
#define K_ELEMS   131072          // 2^17
#define NPOS      ((long long)B_BATCH * A_ELEMS)   // 8388608
#define WS_T_OFF  64              // floats offset: transposed array starts at ws + 64 floats (256 B)
#define WS_NEED   ((size_t)(WS_T_OFF + 2 * B_BATCH * K_ELEMS) * 4)

typedef float v4f __attribute__((ext_vector_type(4)));
typedef float v2f __attribute__((ext_vector_type(2)));

__global__ void zero_ws_kernel(float* ws) {
    ws[0] = 0.0f;   // loss sum
    ws[1] = 0.0f;   // mask count
}

// Pass 1: transpose input (B,2,K) -> wsT (B,K,2) so both channels of one idx
// live in a single 8B dword2 => ONE gather line per position instead of two.
// 2048 blocks x 256 threads x 8 elems = B*K. All reads/writes coalesced.
__global__ __launch_bounds__(256) void transpose_kernel(
    const float* __restrict__ input,
    v2f* __restrict__ wsT)
{
    const long long base = (long long)blockIdx.x * 2048 + threadIdx.x;
    #pragma unroll
    for (int s = 0; s < 8; ++s) {
        long long flat = base + (long long)s * 256;          // b*K + k
        int b = (int)(flat >> 17);
        int k = (int)(flat & (K_ELEMS - 1));
        const float* inb = input + (size_t)b * (2 * K_ELEMS);
        v2f v;
        v.x = inb[k];                // regression[b,0,k]
        v.y = inb[K_ELEMS + k];      // regression[b,1,k]
        wsT[flat] = v;
    }
}

// Pass 2: batch-partitioned main kernel (R12 locality structure kept:
// XCD x owns batches b == x (mod 8) -> 1MB gather window, L2-resident).
// Changes vs R12: single conditional 8B gather per position (4x fewer
// gather transactions), next-g target prefetch issued AFTER the gathers.
__global__ __launch_bounds__(256) void regloss_batched_kernel(
    const v2f* __restrict__ wsT,        // (B, K) x float2
    const v4f* __restrict__ target,     // (B*A) x (x, y, idx, state)
    float* __restrict__ ws)
{
    const int tid = threadIdx.x;
    const int xcd = blockIdx.x & 7;
    const int j   = blockIdx.x >> 3;    // 0..255

    float loss = 0.0f;
    float cnt  = 0.0f;

    // Prologue: targets for g=0 (non-temporal: stream-once).
    v4f tcur[4];
    {
        const int batch = xcd;
        const size_t pos = (size_t)batch * A_ELEMS + (size_t)j * 1024 + (size_t)tid * 4;
        #pragma unroll
        for (int u = 0; u < 4; ++u)
            tcur[u] = __builtin_nontemporal_load(&target[pos + u]);
    }

    #pragma unroll
    for (int g = 0; g < 4; ++g) {
        const int batch = xcd + 8 * g;
        const v2f* __restrict__ wb = wsT + (size_t)batch * K_ELEMS;

        // Conditional single-dword2 gathers (masked lanes: no transaction).
        v2f gv[4];
        float m[4];
        #pragma unroll
        for (int u = 0; u < 4; ++u) {
            int idx = (int)tcur[u].z;
            idx = min(max(idx, 0), K_ELEMS - 1);
            m[u] = (tcur[u].w == 1.0f) ? 1.0f : 0.0f;
            v2f g2; g2.x = 0.0f; g2.y = 0.0f;
            if (m[u] != 0.0f) g2 = wb[idx];
            gv[u] = g2;
        }

        // Prefetch next g's targets AFTER the gathers: the gather-result
        // wait (vmcnt) then leaves these in flight under the compute.
        v4f tnext[4];
        if (g < 3) {
            const int nb = xcd + 8 * (g + 1);
            const size_t pos = (size_t)nb * A_ELEMS + (size_t)j * 1024 + (size_t)tid * 4;
            #pragma unroll
            for (int u = 0; u < 4; ++u)
                tnext[u] = __builtin_nontemporal_load(&target[pos + u]);
        }

        #pragma unroll
        for (int u = 0; u < 4; ++u) {
            float dx = gv[u].x - tcur[u].x;
            float dy = gv[u].y - tcur[u].y;
            float adx = fabsf(dx), ady = fabsf(dy);
            float lx = (adx < 1.0f) ? 0.5f * dx * dx : adx - 0.5f;
            float ly = (ady < 1.0f) ? 0.5f * dy * dy : ady - 0.5f;
            loss += m[u] * (lx + ly);
            cnt  += m[u];
        }

        if (g < 3) {
            #pragma unroll
            for (int u = 0; u < 4; ++u) tcur[u] = tnext[u];
        }
    }

    // Wave-64 butterfly reduce
    #pragma unroll
    for (int off = 32; off > 0; off >>= 1) {
        loss += __shfl_down(loss, off, 64);
        cnt  += __shfl_down(cnt,  off, 64);
    }
    __shared__ float sl[4], sc[4];
    const int wave = tid >> 6, lane = tid & 63;
    if (lane == 0) { sl[wave] = loss; sc[wave] = cnt; }
    __syncthreads();
    if (tid == 0) {
        atomicAdd(&ws[0], sl[0] + sl[1] + sl[2] + sl[3]);
        atomicAdd(&ws[1], sc[0] + sc[1] + sc[2] + sc[3]);
    }
}

// Fallback (R12 structure, original layout) if ws_size can't hold the
// transposed copy or sizes differ.
__global__ __launch_bounds__(256) void regloss_generic_kernel(
    const float* __restrict__ input,
    const v4f* __restrict__ target,
    float* __restrict__ ws,
    long long N, int K, int ashift)
{
    long long tid    = (long long)blockIdx.x * blockDim.x + threadIdx.x;
    long long stride = (long long)gridDim.x * blockDim.x;
    float loss = 0.0f, cnt = 0.0f;
    for (long long i = tid; i < N; i += stride) {
        v4f t = target[i];
        if (t.w == 1.0f) {
            int b   = (int)(i >> ashift);
            int idx = min(max((int)t.z, 0), K - 1);
            const float* inb = input + (long long)b * (2LL * K);
            float dx = inb[idx] - t.x;
            float dy = inb[K + idx] - t.y;
            float adx = fabsf(dx), ady = fabsf(dy);
            loss += (adx < 1.0f) ? 0.5f * dx * dx : adx - 0.5f;
            loss += (ady < 1.0f) ? 0.5f * dy * dy : ady - 0.5f;
            cnt  += 1.0f;
        }
    }
    #pragma unroll
    for (int off = 32; off > 0; off >>= 1) {
        loss += __shfl_down(loss, off, 64);
        cnt  += __shfl_down(cnt,  off, 64);
    }
    __shared__ float sl[4], sc[4];
    int wave = threadIdx.x >> 6, lane = threadIdx.x & 63;
    if (lane == 0) { sl[wave] = loss; sc[wave] = cnt; }
    __syncthreads();
    if (threadIdx.x == 0) {
        atomicAdd(&ws[0], sl[0] + sl[1] + sl[2] + sl[3]);
        atomicAdd(&ws[1], sc[0] + sc[1] + sc[2] + sc[3]);
    }
}

__global__ void finalize_kernel(const float* __restrict__ ws,
                                float* __restrict__ out) {
    const float POLY_WEIGHT = 1.0f;
    out[0] = ws[0] / fmaxf(1.0f, ws[1]) * POLY_WEIGHT;
}

extern "C" void kernel_launch(void* const* d_in, const int* in_sizes, int n_in,
                              void* d_out, int out_size, void* d_ws, size_t ws_size,
                              hipStream_t stream) {
    const float* input  = (const float*)d_in[0];   // (B, 2K) f32
    const v4f*   target = (const v4f*)d_in[1];     // (B, A, 4) f32
    float* out = (float*)d_out;
    float* ws  = (float*)d_ws;

    long long N = (long long)in_sizes[1] / 4;      // B*A

    zero_ws_kernel<<<1, 1, 0, stream>>>(ws);

    const bool shapes_ok = (N == NPOS) && (in_sizes[0] == 2 * K_ELEMS * B_BATCH);
    if (shapes_ok && ws_size >= WS_NEED) {
        v2f* wsT = (v2f*)(ws + WS_T_OFF);
        transpose_kernel<<<2048, 256, 0, stream>>>(input, wsT);
        regloss_batched_kernel<<<2048, 256, 0, stream>>>(wsT, target, ws);
    } else {
        regloss_generic_kernel<<<2048, 256, 0, stream>>>(input, target, ws,
                                                         N, K_ELEMS, A_SHIFT);
    }

    finalize_kernel<<<1, 1, 0, stream>>>(ws, out);
}

// Round 14
// 256.764 us; speedup vs baseline: 1.3337x; 1.0132x over previous
//
#include <hip/hip_runtime.h>

// Problem constants (from reference): B=32, A=262144, K=131072.
#define B_BATCH   32
#define A_ELEMS   262144
#define A_SHIFT   18
#define K_ELEMS   131072          // 2^17
#define NPOS      ((long long)B_BATCH * A_ELEMS)   // 8388608
#define WS_T_OFF  64              // floats: transposed array starts at ws + 256 B
#define WS_NEED   ((size_t)(WS_T_OFF + 2 * B_BATCH * K_ELEMS) * 4)

typedef float v4f __attribute__((ext_vector_type(4)));
typedef float v2f __attribute__((ext_vector_type(2)));

__global__ void zero_ws_kernel(float* ws) {
    ws[0] = 0.0f;   // loss sum
    ws[1] = 0.0f;   // mask count
}

// Pass 1: transpose input (B,2,K) -> wsT (B,K,2): both channels of one idx in
// a single 8B dword2 => one gather line per position. 33.5MB each way (~11us).
__global__ __launch_bounds__(256) void transpose_kernel(
    const float* __restrict__ input,
    v2f* __restrict__ wsT)
{
    const long long base = (long long)blockIdx.x * 2048 + threadIdx.x;
    #pragma unroll
    for (int s = 0; s < 8; ++s) {
        long long flat = base + (long long)s * 256;          // b*K + k
        int b = (int)(flat >> 17);
        int k = (int)(flat & (K_ELEMS - 1));
        const float* inb = input + (size_t)b * (2 * K_ELEMS);
        v2f v;
        v.x = inb[k];                // regression[b,0,k]
        v.y = inb[K_ELEMS + k];      // regression[b,1,k]
        wsT[flat] = v;
    }
}

// Pass 2: batch-partitioned (XCD x owns batches b == x mod 8 -> 1MB L2-resident
// gather window). R13 lesson: per-g wait->gather->wait serialization left only
// ~4 loads in flight. Full phase-split: A) issue ALL 16 target loads, B) per-g
// consume targets + issue all 16 conditional gathers, C) compute. ~32 memory
// ops in flight per wave; VGPR-heavy by design.
__global__ __launch_bounds__(256) void regloss_batched_kernel(
    const v2f* __restrict__ wsT,        // (B, K) x float2
    const v4f* __restrict__ target,     // (B*A) x (x, y, idx, state)
    float* __restrict__ ws)
{
    const int tid = threadIdx.x;
    const int xcd = blockIdx.x & 7;
    const int j   = blockIdx.x >> 3;    // 0..255

    // ---- Phase A: issue all 16 non-temporal target loads ----
    v4f t[16];
    #pragma unroll
    for (int g = 0; g < 4; ++g) {
        const int batch = xcd + 8 * g;
        const size_t pos = (size_t)batch * A_ELEMS + (size_t)j * 1024
                         + (size_t)tid * 4;
        #pragma unroll
        for (int u = 0; u < 4; ++u)
            t[4 * g + u] = __builtin_nontemporal_load(&target[pos + u]);
    }

    // ---- Phase B: consume targets, issue all 16 conditional gathers ----
    float tx[16], ty[16], m[16];
    v2f gv[16];
    #pragma unroll
    for (int g = 0; g < 4; ++g) {
        const int batch = xcd + 8 * g;
        const v2f* __restrict__ wb = wsT + (size_t)batch * K_ELEMS;
        #pragma unroll
        for (int u = 0; u < 4; ++u) {
            const int p = 4 * g + u;
            v4f tv = t[p];                       // vmcnt wait lands here
            tx[p] = tv.x;
            ty[p] = tv.y;
            int idx = (int)tv.z;
            idx = min(max(idx, 0), K_ELEMS - 1);
            m[p] = (tv.w == 1.0f) ? 1.0f : 0.0f;
            v2f g2; g2.x = 0.0f; g2.y = 0.0f;
            if (m[p] != 0.0f) g2 = wb[idx];      // exec-masked 8B gather
            gv[p] = g2;
        }
    }

    // ---- Phase C: compute (gather waits resolve here, 16 deep) ----
    float loss = 0.0f;
    float cnt  = 0.0f;
    #pragma unroll
    for (int p = 0; p < 16; ++p) {
        float dx = gv[p].x - tx[p];
        float dy = gv[p].y - ty[p];
        float adx = fabsf(dx), ady = fabsf(dy);
        float lx = (adx < 1.0f) ? 0.5f * dx * dx : adx - 0.5f;
        float ly = (ady < 1.0f) ? 0.5f * dy * dy : ady - 0.5f;
        loss += m[p] * (lx + ly);
        cnt  += m[p];
    }

    // Wave-64 butterfly reduce
    #pragma unroll
    for (int off = 32; off > 0; off >>= 1) {
        loss += __shfl_down(loss, off, 64);
        cnt  += __shfl_down(cnt,  off, 64);
    }
    __shared__ float sl[4], sc[4];
    const int wave = tid >> 6, lane = tid & 63;
    if (lane == 0) { sl[wave] = loss; sc[wave] = cnt; }
    __syncthreads();
    if (tid == 0) {
        atomicAdd(&ws[0], sl[0] + sl[1] + sl[2] + sl[3]);
        atomicAdd(&ws[1], sc[0] + sc[1] + sc[2] + sc[3]);
    }
}

// Fallback (original layout) if sizes differ or ws too small.
__global__ __launch_bounds__(256) void regloss_generic_kernel(
    const float* __restrict__ input,
    const v4f* __restrict__ target,
    float* __restrict__ ws,
    long long N, int K, int ashift)
{
    long long tid    = (long long)blockIdx.x * blockDim.x + threadIdx.x;
    long long stride = (long long)gridDim.x * blockDim.x;
    float loss = 0.0f, cnt = 0.0f;
    for (long long i = tid; i < N; i += stride) {
        v4f t = target[i];
        if (t.w == 1.0f) {
            int b   = (int)(i >> ashift);
            int idx = min(max((int)t.z, 0), K - 1);
            const float* inb = input + (long long)b * (2LL * K);
            float dx = inb[idx] - t.x;
            float dy = inb[K + idx] - t.y;
            float adx = fabsf(dx), ady = fabsf(dy);
            loss += (adx < 1.0f) ? 0.5f * dx * dx : adx - 0.5f;
            loss += (ady < 1.0f) ? 0.5f * dy * dy : ady - 0.5f;
            cnt  += 1.0f;
        }
    }
    #pragma unroll
    for (int off = 32; off > 0; off >>= 1) {
        loss += __shfl_down(loss, off, 64);
        cnt  += __shfl_down(cnt,  off, 64);
    }
    __shared__ float sl[4], sc[4];
    int wave = threadIdx.x >> 6, lane = threadIdx.x & 63;
    if (lane == 0) { sl[wave] = loss; sc[wave] = cnt; }
    __syncthreads();
    if (threadIdx.x == 0) {
        atomicAdd(&ws[0], sl[0] + sl[1] + sl[2] + sl[3]);
        atomicAdd(&ws[1], sc[0] + sc[1] + sc[2] + sc[3]);
    }
}

__global__ void finalize_kernel(const float* __restrict__ ws,
                                float* __restrict__ out) {
    const float POLY_WEIGHT = 1.0f;
    out[0] = ws[0] / fmaxf(1.0f, ws[1]) * POLY_WEIGHT;
}

extern "C" void kernel_launch(void* const* d_in, const int* in_sizes, int n_in,
                              void* d_out, int out_size, void* d_ws, size_t ws_size,
                              hipStream_t stream) {
    const float* input  = (const float*)d_in[0];   // (B, 2K) f32
    const v4f*   target = (const v4f*)d_in[1];     // (B, A, 4) f32
    float* out = (float*)d_out;
    float* ws  = (float*)d_ws;

    long long N = (long long)in_sizes[1] / 4;      // B*A

    zero_ws_kernel<<<1, 1, 0, stream>>>(ws);

    const bool shapes_ok = (N == NPOS) && (in_sizes[0] == 2 * K_ELEMS * B_BATCH);
    if (shapes_ok && ws_size >= WS_NEED) {
        v2f* wsT = (v2f*)(ws + WS_T_OFF);
        transpose_kernel<<<2048, 256, 0, stream>>>(input, wsT);
        regloss_batched_kernel<<<2048, 256, 0, stream>>>(wsT, target, ws);
    } else {
        regloss_generic_kernel<<<2048, 256, 0, stream>>>(input, target, ws,
                                                         N, K_ELEMS, A_SHIFT);
    }

    finalize_kernel<<<1, 1, 0, stream>>>(ws, out);
}